// Round 3
// baseline (1685.223 us; speedup 1.0000x reference)
//
#include <hip/hip_runtime.h>

// ---------------------------------------------------------------------------
// SpatiotemporalSlotAttention on MI355X (gfx950). B=16,S=4096,D=1024,K=16,3 it.
// Round 6: algebraic elimination of K/V projections.
//   logits = (lnS @ (Wq^T Wk)) @ tok^T + (bq@Wk)@tok^T-col-bias + q.bk
//   gi     = (attn_n @ tok) @ (W_ih Wv)^T + (W_ih bv + b_ih)
// Prologue: P^T = Wk^T@Wq and Wihv = W_ih@Wv via gemm128_bb; attn passes read
// bf16 tokens directly (134 MB, L3-resident across iterations).
// ---------------------------------------------------------------------------

typedef unsigned short u16;
typedef unsigned int u32;
typedef float f32x4 __attribute__((ext_vector_type(4)));
typedef unsigned int u32x4 __attribute__((ext_vector_type(4)));
typedef __bf16 bf16x8 __attribute__((ext_vector_type(8)));

#define B_ 16
#define S_ 4096
#define D_ 1024
#define K_ 16
#define SCALE_ 0.03125f

__device__ __forceinline__ float b2f(u16 u) {
  u32 x = ((u32)u) << 16;
  return __builtin_bit_cast(float, x);
}
__device__ __forceinline__ u16 f2b(float f) {
  u32 u = __builtin_bit_cast(u32, f);
  u32 r = (u + 0x7fffu + ((u >> 16) & 1u)) >> 16;  // RNE
  return (u16)r;
}
__device__ __forceinline__ bf16x8 ld16g(const u16* p) {
  return __builtin_bit_cast(bf16x8, *(const u32x4*)p);
}
__device__ __forceinline__ void gload_lds16(const void* g, void* l) {
  __builtin_amdgcn_global_load_lds(
      (const __attribute__((address_space(1))) void*)g,
      (__attribute__((address_space(3))) void*)l, 16, 0, 0);
}

// fp32 -> bf16, 8 elements/thread (vectorized: 32B in, 16B out)
__global__ void convert8_kernel(const float* __restrict__ src,
                                u16* __restrict__ dst, int n8) {
  const int idx = blockIdx.x * 256 + threadIdx.x;
  if (idx >= n8) return;
  const float* s = src + (size_t)idx * 8;
  const f32x4 lo = *(const f32x4*)s;
  const f32x4 hi = *(const f32x4*)(s + 4);
  union { u16 h[8]; u32x4 q; } u;
#pragma unroll
  for (int j = 0; j < 4; ++j) { u.h[j] = f2b(lo[j]); u.h[4 + j] = f2b(hi[j]); }
  *(u32x4*)(dst + (size_t)idx * 8) = u.q;
}

// fp32 [R x C] -> bf16 transposed [C x R]. 64x64 tiles, coalesced reads.
__global__ __launch_bounds__(256) void transcvt_kernel(
    const float* __restrict__ src, u16* __restrict__ dst, int R, int C) {
  const int r0 = blockIdx.x * 64;
  const int c0 = blockIdx.y * 64;
  const int cl = threadIdx.x & 63;
  const int rq = threadIdx.x >> 6;  // 0..3
#pragma unroll
  for (int h = 0; h < 2; ++h) {
    const int rbase = (rq + h * 4) * 8;
    union { u16 u[8]; u32x4 q; } w;
#pragma unroll
    for (int j = 0; j < 8; ++j)
      w.u[j] = f2b(src[(size_t)(r0 + rbase + j) * C + c0 + cl]);
    *(u32x4*)&dst[(size_t)(c0 + cl) * R + r0 + rbase] = w.q;
  }
}

// out[c] = sum_r W[r*C+c] * x[r]   (column-weighted sum; prologue only)
__global__ void colvec_kernel(const float* __restrict__ W,
                              const float* __restrict__ x,
                              float* __restrict__ out, int R, int C) {
  const int c = blockIdx.x * 256 + threadIdx.x;
  if (c >= C) return;
  float acc = 0.f;
  for (int r = 0; r < R; ++r) acc = fmaf(W[(size_t)r * C + c], x[r], acc);
  out[c] = acc;
}

// out[r] = add[r] + sum_c W[r*C+c] * x[c]   (one wave per row; prologue only)
__global__ __launch_bounds__(256) void rowvec_kernel(
    const float* __restrict__ W, const float* __restrict__ x,
    const float* __restrict__ add, float* __restrict__ out, int R, int C) {
  const int wave = threadIdx.x >> 6, lane = threadIdx.x & 63;
  const int r = blockIdx.x * 4 + wave;
  if (r >= R) return;
  float acc = 0.f;
  for (int c = lane; c < C; c += 64) acc = fmaf(W[(size_t)r * C + c], x[c], acc);
#pragma unroll
  for (int off = 1; off < 64; off <<= 1) acc += __shfl_xor(acc, off);
  if (lane == 0) out[r] = add[r] + acc;
}

// qdot[m] = lnS_bf16[m,:].qd_w + bq.bk   (exact q.bk logit term; 256 rows)
__global__ __launch_bounds__(256) void qdot_kernel(
    const u16* __restrict__ lnq, const float* __restrict__ qdw,
    const float* __restrict__ bq, const float* __restrict__ bk,
    float* __restrict__ out) {
  const int wave = threadIdx.x >> 6, lane = threadIdx.x & 63;
  const int m = blockIdx.x * 4 + wave;
  float acc = 0.f;
  for (int a = lane; a < D_; a += 64)
    acc = fmaf(b2f(lnq[(size_t)m * D_ + a]), qdw[a], acc);
  for (int d = lane; d < D_; d += 64) acc = fmaf(bq[d], bk[d], acc);
#pragma unroll
  for (int off = 1; off < 64; off <<= 1) acc += __shfl_xor(acc, off);
  if (lane == 0) out[m] = acc;
}

// ---------------------------------------------------------------------------
// Big bt-GEMM: C(bf16, MxN) = A(bf16 MxKd) @ Bw(bf16 NxKd)^T [+ bias].
// 128x128 tile, 4 waves, global_load_lds staging, both-sides XOR swizzle,
// XCD-chunked 1D grid (nwg % 8 == 0). Now prologue-only (P^T, Wihv).
// ---------------------------------------------------------------------------
__global__ __launch_bounds__(256) void gemm128_bb(
    const u16* __restrict__ A, const u16* __restrict__ Bw,
    const float* __restrict__ bias, u16* __restrict__ C, int N, int Kd,
    int mtiles) {
  __shared__ __align__(16) u16 At[128 * 64];
  __shared__ __align__(16) u16 Bt[128 * 64];
  const int tid = threadIdx.x;
  const int ntiles = N >> 7;
  const int nwg = mtiles * ntiles;
  const int cpx = nwg >> 3;  // blocks per XCD (nwg % 8 == 0)
  const int lin = blockIdx.x;
  const int wg = (lin & 7) * cpx + (lin >> 3);
  const int m0 = (wg / ntiles) * 128;
  const int n0 = (wg % ntiles) * 128;
  const int wave = tid >> 6, lane = tid & 63;
  const int q4 = lane >> 4, l16 = lane & 15;
  const int wm = (wave & 1) * 64, wn = (wave >> 1) * 64;

  f32x4 acc[4][4];
#pragma unroll
  for (int i = 0; i < 4; ++i)
#pragma unroll
    for (int j = 0; j < 4; ++j) acc[i][j] = 0.f;

  const int trow = tid >> 3;                             // 0..31
  const int tcol = ((tid & 7) * 8) ^ ((trow & 7) << 3);  // pre-swizzled col
  const u16* ga = A + (size_t)(m0 + trow) * Kd + tcol;
  const u16* gb = Bw + (size_t)(n0 + trow) * Kd + tcol;
  u16* la = At + tid * 8;
  u16* lb = Bt + tid * 8;

  for (int k0 = 0; k0 < Kd; k0 += 64) {
    __syncthreads();
#pragma unroll
    for (int c = 0; c < 4; ++c)
      gload_lds16(ga + (size_t)c * 32 * Kd + k0, la + c * 2048);
#pragma unroll
    for (int c = 0; c < 4; ++c)
      gload_lds16(gb + (size_t)c * 32 * Kd + k0, lb + c * 2048);
    __syncthreads();
#pragma unroll
    for (int kk = 0; kk < 64; kk += 32) {
      bf16x8 af[4], bfr[4];
#pragma unroll
      for (int i = 0; i < 4; ++i) {
        const int row = wm + i * 16 + l16;
        const int byo = row * 128 + ((kk * 2 + q4 * 16) ^ ((row & 7) << 4));
        af[i] = *(const bf16x8*)((const char*)At + byo);
      }
#pragma unroll
      for (int j = 0; j < 4; ++j) {
        const int row = wn + j * 16 + l16;
        const int byo = row * 128 + ((kk * 2 + q4 * 16) ^ ((row & 7) << 4));
        bfr[j] = *(const bf16x8*)((const char*)Bt + byo);
      }
#pragma unroll
      for (int i = 0; i < 4; ++i)
#pragma unroll
        for (int j = 0; j < 4; ++j)
          acc[i][j] = __builtin_amdgcn_mfma_f32_16x16x32_bf16(af[i], bfr[j],
                                                              acc[i][j], 0, 0, 0);
    }
  }
#pragma unroll
  for (int j = 0; j < 4; ++j) {
    const int col = n0 + wn + j * 16 + l16;
    const float bv = bias ? bias[col] : 0.f;
#pragma unroll
    for (int i = 0; i < 4; ++i) {
      const int rowb = m0 + wm + i * 16 + q4 * 4;
#pragma unroll
      for (int r = 0; r < 4; ++r)
        C[(size_t)(rowb + r) * N + col] = f2b(acc[i][j][r] + bv);
    }
  }
}

// ---------------------------------------------------------------------------
// Small bt-GEMM (M=256): 64x64 tile, 4 waves of 32x32. A,Bw bf16, bias fp32.
// MODE 0: bf16 out | 1: f32 out | 2: gelu->bf16 | 3: +resid -> f32
// ---------------------------------------------------------------------------
template <int MODE>
__global__ __launch_bounds__(256) void gemm64_bt(
    const u16* __restrict__ A, const u16* __restrict__ Bw,
    const float* __restrict__ bias, float* Cf, u16* Cb, const float* resid,
    int N, int Kd) {
  __shared__ __align__(16) u16 At[64 * 64];
  __shared__ __align__(16) u16 Bt[64 * 64];
  const int tid = threadIdx.x;
  const int m0 = blockIdx.x * 64;
  const int n0 = blockIdx.y * 64;
  const int wave = tid >> 6, lane = tid & 63;
  const int q4 = lane >> 4, l16 = lane & 15;
  const int wm = (wave & 1) * 32, wn = (wave >> 1) * 32;

  f32x4 acc[2][2];
#pragma unroll
  for (int i = 0; i < 2; ++i)
#pragma unroll
    for (int j = 0; j < 2; ++j) acc[i][j] = 0.f;

  const int r_ = tid >> 3;
  const int c8 = (tid & 7) * 8;

  for (int k0 = 0; k0 < Kd; k0 += 64) {
    u32x4 ta[2], tb[2];
#pragma unroll
    for (int i = 0; i < 2; ++i) {
      ta[i] = *(const u32x4*)(A + (size_t)(m0 + r_ + i * 32) * Kd + k0 + c8);
      tb[i] = *(const u32x4*)(Bw + (size_t)(n0 + r_ + i * 32) * Kd + k0 + c8);
    }
    __syncthreads();
#pragma unroll
    for (int i = 0; i < 2; ++i) {
      *(u32x4*)&At[(r_ + i * 32) * 64 + c8] = ta[i];
      *(u32x4*)&Bt[(r_ + i * 32) * 64 + c8] = tb[i];
    }
    __syncthreads();
#pragma unroll
    for (int kk = 0; kk < 64; kk += 32) {
      bf16x8 af[2], bfr[2];
#pragma unroll
      for (int i = 0; i < 2; ++i)
        af[i] = *(const bf16x8*)&At[(wm + i * 16 + l16) * 64 + kk + q4 * 8];
#pragma unroll
      for (int j = 0; j < 2; ++j)
        bfr[j] = *(const bf16x8*)&Bt[(wn + j * 16 + l16) * 64 + kk + q4 * 8];
#pragma unroll
      for (int i = 0; i < 2; ++i)
#pragma unroll
        for (int j = 0; j < 2; ++j)
          acc[i][j] = __builtin_amdgcn_mfma_f32_16x16x32_bf16(af[i], bfr[j],
                                                              acc[i][j], 0, 0, 0);
    }
  }
#pragma unroll
  for (int j = 0; j < 2; ++j) {
    const int col = n0 + wn + j * 16 + l16;
    const float bv = bias[col];
#pragma unroll
    for (int i = 0; i < 2; ++i) {
      const int rowb = m0 + wm + i * 16 + q4 * 4;
#pragma unroll
      for (int r = 0; r < 4; ++r) {
        const int row = rowb + r;
        float val = acc[i][j][r] + bv;
        if constexpr (MODE == 0) {
          Cb[(size_t)row * N + col] = f2b(val);
        } else if constexpr (MODE == 1) {
          Cf[(size_t)row * N + col] = val;
        } else if constexpr (MODE == 2) {
          val = 0.5f * val * (1.f + erff(val * 0.70710678118654752f));
          Cb[(size_t)row * N + col] = f2b(val);
        } else {
          const float rv = resid[(size_t)row * N + col];
          Cf[(size_t)row * N + col] = val + rv;
        }
      }
    }
  }
}

// ---------------------------------------------------------------------------
// attn pass 1: logits = qk@tok^T * SCALE + qdot, softmax over K (slots)
// -> attn_t (B,S,16) f32 + rowsum atomics; optional f32 attn (B,K,S) out.
// ---------------------------------------------------------------------------
__global__ __launch_bounds__(256) void attn_pass1(
    const u16* __restrict__ qb, const u16* __restrict__ tok,
    const float* __restrict__ qdot, float* __restrict__ attn_t,
    float* __restrict__ rowsum, float* __restrict__ attn_out) {
  const int b = blockIdx.y;
  const int wave = threadIdx.x >> 6, lane = threadIdx.x & 63;
  const int q4 = lane >> 4, l16 = lane & 15;
  const int tok0 = blockIdx.x * 256 + wave * 64;
  const u16* ap = qb + (size_t)(b * 16 + l16) * D_ + q4 * 8;
  const u16* bp = tok + ((size_t)b * S_ + tok0 + l16) * D_ + q4 * 8;
  const f32x4 qd = *(const f32x4*)&qdot[b * 16 + q4 * 4];
  f32x4 acc[4];
#pragma unroll
  for (int j = 0; j < 4; ++j) acc[j] = 0.f;
  for (int k0 = 0; k0 < D_; k0 += 32) {
    bf16x8 a = ld16g(ap + k0);
#pragma unroll
    for (int j = 0; j < 4; ++j) {
      bf16x8 bb = ld16g(bp + (size_t)j * 16 * D_ + k0);
      acc[j] = __builtin_amdgcn_mfma_f32_16x16x32_bf16(a, bb, acc[j], 0, 0, 0);
    }
  }
  float rs[4] = {0.f, 0.f, 0.f, 0.f};
#pragma unroll
  for (int j = 0; j < 4; ++j) {
    const int token = tok0 + j * 16 + l16;
    float l[4];
#pragma unroll
    for (int r = 0; r < 4; ++r) l[r] = acc[j][r] * SCALE_ + qd[r];
    float mx = fmaxf(fmaxf(l[0], l[1]), fmaxf(l[2], l[3]));
    mx = fmaxf(mx, __shfl_xor(mx, 16));
    mx = fmaxf(mx, __shfl_xor(mx, 32));
    float e[4], ssum = 0.f;
#pragma unroll
    for (int r = 0; r < 4; ++r) { e[r] = __expf(l[r] - mx); ssum += e[r]; }
    ssum += __shfl_xor(ssum, 16);
    ssum += __shfl_xor(ssum, 32);
    const float inv = 1.f / ssum;
    f32x4 p;
#pragma unroll
    for (int r = 0; r < 4; ++r) { p[r] = e[r] * inv; rs[r] += p[r]; }
    *(f32x4*)(attn_t + ((size_t)b * S_ + token) * 16 + q4 * 4) = p;
    if (attn_out) {
#pragma unroll
      for (int r = 0; r < 4; ++r)
        attn_out[(size_t)(b * 16 + q4 * 4 + r) * S_ + token] = p[r];
    }
  }
#pragma unroll
  for (int r = 0; r < 4; ++r) {
    float v = rs[r];
    v += __shfl_xor(v, 1);
    v += __shfl_xor(v, 2);
    v += __shfl_xor(v, 4);
    v += __shfl_xor(v, 8);
    if (l16 == 0) atomicAdd(&rowsum[b * 16 + q4 * 4 + r], v);
  }
}

// ---------------------------------------------------------------------------
// attn pass 2: uprime[b,k,e] += sum_s attn_t[b,s,k] * tok[b,s,e].
// ---------------------------------------------------------------------------
__global__ __launch_bounds__(256) void attn_pass2(
    const float* __restrict__ attn_t, const u16* __restrict__ tok,
    float* __restrict__ uprime) {
  const int b = blockIdx.y;
  const int dchunk = blockIdx.x & 1;
  const int ssplit = blockIdx.x >> 1;
  const int d = dchunk * 512 + threadIdx.x * 2;
  const int s0 = ssplit * 512;
  const u16* vp = tok + ((size_t)b * S_ + s0) * D_ + d;
  const float* ap = attn_t + ((size_t)b * S_ + s0) * 16;
  float acc0[16], acc1[16];
#pragma unroll
  for (int k = 0; k < 16; ++k) { acc0[k] = 0.f; acc1[k] = 0.f; }
#pragma unroll 4
  for (int s = 0; s < 512; ++s) {
    const u32 vv2 = *(const u32*)(vp + (size_t)s * D_);
    const float v0 = b2f((u16)(vv2 & 0xffffu));
    const float v1 = b2f((u16)(vv2 >> 16));
    const float* ar = ap + s * 16;
#pragma unroll
    for (int k = 0; k < 16; ++k) {
      const float a = ar[k];
      acc0[k] = fmaf(a, v0, acc0[k]);
      acc1[k] = fmaf(a, v1, acc1[k]);
    }
  }
#pragma unroll
  for (int k = 0; k < 16; ++k) {
    atomicAdd(&uprime[(size_t)(b * 16 + k) * D_ + d], acc0[k]);
    atomicAdd(&uprime[(size_t)(b * 16 + k) * D_ + d + 1], acc1[k]);
  }
}

__global__ void normcvt_kernel(const float* __restrict__ updates,
                               const float* __restrict__ rowsum,
                               u16* __restrict__ out) {
  const int idx = blockIdx.x * 256 + threadIdx.x;
  const int m = idx >> 10;
  const float inv = 1.f / (rowsum[m] + 1e-8f);
  out[idx] = f2b(updates[idx] * inv);
}

// LayerNorm (256,1024) f32 -> bf16 (+ optional raw bf16 copy). g,b fp32.
__global__ __launch_bounds__(256) void ln_kernel(
    const float* __restrict__ x, const float* __restrict__ g,
    const float* __restrict__ bb, u16* __restrict__ out_ln,
    u16* __restrict__ out_raw) {
  const int row = blockIdx.x, tid = threadIdx.x;
  const float* xr = x + (size_t)row * D_;
  float v[4], s = 0.f, ss = 0.f;
#pragma unroll
  for (int i = 0; i < 4; ++i) {
    v[i] = xr[tid + i * 256];
    s += v[i];
    ss += v[i] * v[i];
  }
#pragma unroll
  for (int off = 1; off < 64; off <<= 1) {
    s += __shfl_xor(s, off);
    ss += __shfl_xor(ss, off);
  }
  __shared__ float sh[8];
  if ((tid & 63) == 0) { sh[tid >> 6] = s; sh[4 + (tid >> 6)] = ss; }
  __syncthreads();
  s = sh[0] + sh[1] + sh[2] + sh[3];
  ss = sh[4] + sh[5] + sh[6] + sh[7];
  const float mu = s * (1.f / 1024.f);
  float var = ss * (1.f / 1024.f) - mu * mu;
  var = fmaxf(var, 0.f);
  const float rstd = rsqrtf(var + 1e-5f);
#pragma unroll
  for (int i = 0; i < 4; ++i) {
    const int dd = tid + i * 256;
    out_ln[(size_t)row * D_ + dd] =
        f2b((v[i] - mu) * rstd * g[dd] + bb[dd]);
    if (out_raw) out_raw[(size_t)row * D_ + dd] = f2b(v[i]);
  }
}

__global__ void gru_kernel(const float* __restrict__ gi,
                           const float* __restrict__ gh,
                           float* __restrict__ slots) {
  const int idx = blockIdx.x * 256 + threadIdx.x;
  const int m = idx >> 10, dd = idx & 1023;
  const size_t base = (size_t)m * 3072 + dd;
  const float ir = gi[base], iz = gi[base + 1024], in_ = gi[base + 2048];
  const float hr = gh[base], hz = gh[base + 1024], hn = gh[base + 2048];
  const float r = 1.f / (1.f + __expf(-(ir + hr)));
  const float z = 1.f / (1.f + __expf(-(iz + hz)));
  const float n = tanhf(in_ + r * hn);
  slots[idx] = (1.f - z) * n + z * slots[idx];
}

__global__ void init_slots_kernel(const float* __restrict__ mu,
                                  float* __restrict__ slots) {
  const int idx = blockIdx.x * 256 + threadIdx.x;
  slots[idx] = mu[idx & (K_ * D_ - 1)];
}

__global__ void store_slots_kernel(const float* __restrict__ slots,
                                   float* __restrict__ out) {
  const int idx = blockIdx.x * 256 + threadIdx.x;
  out[idx] = slots[idx];
}

// ---------------------------------------------------------------------------
extern "C" void kernel_launch(void* const* d_in, const int* in_sizes, int n_in,
                              void* d_out, int out_size, void* d_ws,
                              size_t ws_size, hipStream_t stream) {
  const float* tokens = (const float*)d_in[0];
  const float* slot_mu = (const float*)d_in[1];
  const float* Wq = (const float*)d_in[2];
  const float* bq = (const float*)d_in[3];
  const float* Wk = (const float*)d_in[4];
  const float* bk = (const float*)d_in[5];
  const float* Wv = (const float*)d_in[6];
  const float* bv = (const float*)d_in[7];
  const float* W_ih = (const float*)d_in[8];
  const float* b_ih = (const float*)d_in[9];
  const float* W_hh = (const float*)d_in[10];
  const float* b_hh = (const float*)d_in[11];
  const float* W1 = (const float*)d_in[12];
  const float* b1 = (const float*)d_in[13];
  const float* W2 = (const float*)d_in[14];
  const float* b2 = (const float*)d_in[15];
  const float* g_slots = (const float*)d_in[16];
  const float* b_slots = (const float*)d_in[17];
  const float* g_mlp = (const float*)d_in[18];
  const float* b_mlp = (const float*)d_in[19];

  char* p = (char*)d_ws;
  auto alloc = [&](size_t bytes) {
    char* r = p;
    p += (bytes + 255) & ~(size_t)255;
    return r;
  };
  u16* tokb = (u16*)alloc((size_t)B_ * S_ * D_ * 2);          // 134 MB bf16 tokens
  float* attn_t = (float*)alloc((size_t)B_ * S_ * K_ * 4);    // 4 MB
  float* slots = (float*)alloc((size_t)B_ * K_ * D_ * 4);     // 1 MB
  float* updates = (float*)alloc((size_t)B_ * K_ * D_ * 4);   // 1 MB (u')
  float* rowsum = (float*)alloc(1024);                        // adjacent to updates
  float* gi = (float*)alloc((size_t)B_ * K_ * 3 * D_ * 4);    // 3 MB
  float* gh = (float*)alloc((size_t)B_ * K_ * 3 * D_ * 4);    // 3 MB
  u16* slots_bf16 = (u16*)alloc((size_t)B_ * K_ * D_ * 2);
  u16* slots_ln_bf16 = (u16*)alloc((size_t)B_ * K_ * D_ * 2);
  u16* qkbuf = (u16*)alloc((size_t)B_ * K_ * D_ * 2);
  u16* updates_bf16 = (u16*)alloc((size_t)B_ * K_ * D_ * 2);
  u16* h_bf16 = (u16*)alloc((size_t)B_ * K_ * D_ * 2);
  u16* act_bf16 = (u16*)alloc((size_t)B_ * K_ * 4 * D_ * 2);  // 2 MB
  float* qdotbuf = (float*)alloc(256 * 4);
  float* qd_w = (float*)alloc(D_ * 4);
  float* qkbias = (float*)alloc(D_ * 4);
  float* bihv = (float*)alloc(3 * D_ * 4);
  // bf16 weight copies / fused products
  u16* cWih = (u16*)alloc((size_t)3 * D_ * D_ * 2);   // W_ih (for Wihv GEMM)
  u16* cWhh = (u16*)alloc((size_t)3 * D_ * D_ * 2);
  u16* cW1 = (u16*)alloc((size_t)4 * D_ * D_ * 2);
  u16* cW2 = (u16*)alloc((size_t)4 * D_ * D_ * 2);
  u16* cWqT = (u16*)alloc((size_t)D_ * D_ * 2);       // Wq^T
  u16* cWkT = (u16*)alloc((size_t)D_ * D_ * 2);       // Wk^T
  u16* cWvT = (u16*)alloc((size_t)D_ * D_ * 2);       // Wv^T
  u16* cPT = (u16*)alloc((size_t)D_ * D_ * 2);        // (Wq^T Wk)^T = Wk^T Wq
  u16* cWihv = (u16*)alloc((size_t)3 * D_ * D_ * 2);  // W_ih @ Wv
  if ((size_t)(p - (char*)d_ws) > ws_size) return;  // ws too small: bail

  float* out_slots = (float*)d_out;                        // (B,K,D) f32
  float* out_attn = (float*)d_out + (size_t)B_ * K_ * D_;  // (B,K,S) f32

  // ---- prologue: converts / transposes -----------------------------------
  convert8_kernel<<<(3 * D_ * D_ / 8 + 255) / 256, 256, 0, stream>>>(W_ih, cWih, 3 * D_ * D_ / 8);
  convert8_kernel<<<(3 * D_ * D_ / 8 + 255) / 256, 256, 0, stream>>>(W_hh, cWhh, 3 * D_ * D_ / 8);
  convert8_kernel<<<(4 * D_ * D_ / 8 + 255) / 256, 256, 0, stream>>>(W1, cW1, 4 * D_ * D_ / 8);
  convert8_kernel<<<(4 * D_ * D_ / 8 + 255) / 256, 256, 0, stream>>>(W2, cW2, 4 * D_ * D_ / 8);
  convert8_kernel<<<(B_ * S_ * D_ / 8 + 255) / 256, 256, 0, stream>>>(
      tokens, tokb, B_ * S_ * D_ / 8);
  transcvt_kernel<<<dim3(16, 16), 256, 0, stream>>>(Wq, cWqT, D_, D_);
  transcvt_kernel<<<dim3(16, 16), 256, 0, stream>>>(Wk, cWkT, D_, D_);
  transcvt_kernel<<<dim3(16, 16), 256, 0, stream>>>(Wv, cWvT, D_, D_);

  // fused weight products:
  // cPT[e,a] = sum_d Wk[d,e] Wq[d,a]  (so per-iter qk = lnS @ cPT^T)
  gemm128_bb<<<64, 256, 0, stream>>>(cWkT, cWqT, nullptr, cPT, D_, D_, 8);
  // cWihv[j,e] = sum_d W_ih[j,d] Wv[d,e]
  gemm128_bb<<<192, 256, 0, stream>>>(cWih, cWvT, nullptr, cWihv, D_, D_, 24);

  // bias folds (exact): qkbias[e] = bq.Wk[:,e]; qd_w[a] = Wq[:,a].bk;
  // bihv[j] = b_ih[j] + W_ih[j,:].bv
  colvec_kernel<<<4, 256, 0, stream>>>(Wk, bq, qkbias, D_, D_);
  colvec_kernel<<<4, 256, 0, stream>>>(Wq, bk, qd_w, D_, D_);
  rowvec_kernel<<<768, 256, 0, stream>>>(W_ih, bv, b_ih, bihv, 3 * D_, D_);

  init_slots_kernel<<<1024, 256, 0, stream>>>(slot_mu, slots);

  for (int it = 0; it < 3; ++it) {
    ln_kernel<<<256, 256, 0, stream>>>(slots, g_slots, b_slots, slots_ln_bf16,
                                       slots_bf16);
    // qk = lnS @ P + qkbias  (replaces q and k projections)
    gemm64_bt<0><<<dim3(4, 16), 256, 0, stream>>>(slots_ln_bf16, cPT, qkbias,
                                                  nullptr, qkbuf, nullptr, D_, D_);
    qdot_kernel<<<64, 256, 0, stream>>>(slots_ln_bf16, qd_w, bq, bk, qdotbuf);
    hipMemsetAsync(updates, 0, (size_t)B_ * K_ * D_ * 4 + 1024, stream);
    attn_pass1<<<dim3(16, 16), 256, 0, stream>>>(
        qkbuf, tokb, qdotbuf, attn_t, rowsum, (it == 2) ? out_attn : nullptr);
    attn_pass2<<<dim3(16, 16), 256, 0, stream>>>(attn_t, tokb, updates);
    normcvt_kernel<<<1024, 256, 0, stream>>>(updates, rowsum, updates_bf16);
    // gi = u'n @ Wihv^T + (W_ih bv + b_ih)   (V projection folded in)
    gemm64_bt<1><<<dim3(4, 48), 256, 0, stream>>>(updates_bf16, cWihv, bihv, gi,
                                                  nullptr, nullptr, 3 * D_, D_);
    gemm64_bt<1><<<dim3(4, 48), 256, 0, stream>>>(slots_bf16, cWhh, b_hh, gh,
                                                  nullptr, nullptr, 3 * D_, D_);
    gru_kernel<<<1024, 256, 0, stream>>>(gi, gh, slots);
    ln_kernel<<<256, 256, 0, stream>>>(slots, g_mlp, b_mlp, h_bf16, nullptr);
    gemm64_bt<2><<<dim3(4, 64), 256, 0, stream>>>(h_bf16, cW1, b1, nullptr,
                                                  act_bf16, nullptr, 4 * D_, D_);
    gemm64_bt<3><<<dim3(4, 16), 256, 0, stream>>>(act_bf16, cW2, b2, slots,
                                                  nullptr, slots, D_, 4 * D_);
  }
  store_slots_kernel<<<1024, 256, 0, stream>>>(slots, out_slots);
}

// Round 4
// 1190.871 us; speedup vs baseline: 1.4151x; 1.4151x over previous
//
#include <hip/hip_runtime.h>

// ---------------------------------------------------------------------------
// SpatiotemporalSlotAttention on MI355X (gfx950). B=16,S=4096,D=1024,K=16,3 it.
// Round 7: fix round-6 regressions.
//  - colvec (bias-fold matvec) was 4-block latency-bound (243 µs x2 per
//    launch): now split-R 64-block atomic version (~8 µs).
//  - gemm64_bt had 1.57M LDS bank conflicts (128-B row stride): apply the
//    same both-sides XOR swizzle proven on gemm128_bb (0 conflicts).
// Structure otherwise unchanged from round 6 (K/V projections eliminated
// algebraically; attn reads bf16 tokens directly).
// ---------------------------------------------------------------------------

typedef unsigned short u16;
typedef unsigned int u32;
typedef float f32x4 __attribute__((ext_vector_type(4)));
typedef unsigned int u32x4 __attribute__((ext_vector_type(4)));
typedef __bf16 bf16x8 __attribute__((ext_vector_type(8)));

#define B_ 16
#define S_ 4096
#define D_ 1024
#define K_ 16
#define SCALE_ 0.03125f

__device__ __forceinline__ float b2f(u16 u) {
  u32 x = ((u32)u) << 16;
  return __builtin_bit_cast(float, x);
}
__device__ __forceinline__ u16 f2b(float f) {
  u32 u = __builtin_bit_cast(u32, f);
  u32 r = (u + 0x7fffu + ((u >> 16) & 1u)) >> 16;  // RNE
  return (u16)r;
}
__device__ __forceinline__ bf16x8 ld16g(const u16* p) {
  return __builtin_bit_cast(bf16x8, *(const u32x4*)p);
}
__device__ __forceinline__ void gload_lds16(const void* g, void* l) {
  __builtin_amdgcn_global_load_lds(
      (const __attribute__((address_space(1))) void*)g,
      (__attribute__((address_space(3))) void*)l, 16, 0, 0);
}

// fp32 -> bf16, 8 elements/thread (vectorized: 32B in, 16B out)
__global__ void convert8_kernel(const float* __restrict__ src,
                                u16* __restrict__ dst, int n8) {
  const int idx = blockIdx.x * 256 + threadIdx.x;
  if (idx >= n8) return;
  const float* s = src + (size_t)idx * 8;
  const f32x4 lo = *(const f32x4*)s;
  const f32x4 hi = *(const f32x4*)(s + 4);
  union { u16 h[8]; u32x4 q; } u;
#pragma unroll
  for (int j = 0; j < 4; ++j) { u.h[j] = f2b(lo[j]); u.h[4 + j] = f2b(hi[j]); }
  *(u32x4*)(dst + (size_t)idx * 8) = u.q;
}

// fp32 [R x C] -> bf16 transposed [C x R]. 64x64 tiles, coalesced reads.
__global__ __launch_bounds__(256) void transcvt_kernel(
    const float* __restrict__ src, u16* __restrict__ dst, int R, int C) {
  const int r0 = blockIdx.x * 64;
  const int c0 = blockIdx.y * 64;
  const int cl = threadIdx.x & 63;
  const int rq = threadIdx.x >> 6;  // 0..3
#pragma unroll
  for (int h = 0; h < 2; ++h) {
    const int rbase = (rq + h * 4) * 8;
    union { u16 u[8]; u32x4 q; } w;
#pragma unroll
    for (int j = 0; j < 8; ++j)
      w.u[j] = f2b(src[(size_t)(r0 + rbase + j) * C + c0 + cl]);
    *(u32x4*)&dst[(size_t)(c0 + cl) * R + r0 + rbase] = w.q;
  }
}

// out[c] += sum_{r in block-chunk} W[r*C+c] * x[r]
// split-R: grid (C/256, R/64); out must be zeroed before launch.
__global__ void colvec_kernel(const float* __restrict__ W,
                              const float* __restrict__ x,
                              float* __restrict__ out, int R, int C) {
  const int c = blockIdx.x * 256 + threadIdx.x;
  const int r0 = blockIdx.y * 64;
  if (c >= C) return;
  float acc = 0.f;
#pragma unroll 8
  for (int r = 0; r < 64; ++r)
    acc = fmaf(W[(size_t)(r0 + r) * C + c], x[r0 + r], acc);
  atomicAdd(&out[c], acc);
}

// out[r] = add[r] + sum_c W[r*C+c] * x[c]   (one wave per row; prologue only)
__global__ __launch_bounds__(256) void rowvec_kernel(
    const float* __restrict__ W, const float* __restrict__ x,
    const float* __restrict__ add, float* __restrict__ out, int R, int C) {
  const int wave = threadIdx.x >> 6, lane = threadIdx.x & 63;
  const int r = blockIdx.x * 4 + wave;
  if (r >= R) return;
  float acc = 0.f;
  for (int c = lane; c < C; c += 64) acc = fmaf(W[(size_t)r * C + c], x[c], acc);
#pragma unroll
  for (int off = 1; off < 64; off <<= 1) acc += __shfl_xor(acc, off);
  if (lane == 0) out[r] = add[r] + acc;
}

// qdot[m] = lnS_bf16[m,:].qd_w + bq.bk   (exact q.bk logit term; 256 rows)
__global__ __launch_bounds__(256) void qdot_kernel(
    const u16* __restrict__ lnq, const float* __restrict__ qdw,
    const float* __restrict__ bq, const float* __restrict__ bk,
    float* __restrict__ out) {
  const int wave = threadIdx.x >> 6, lane = threadIdx.x & 63;
  const int m = blockIdx.x * 4 + wave;
  float acc = 0.f;
  for (int a = lane; a < D_; a += 64)
    acc = fmaf(b2f(lnq[(size_t)m * D_ + a]), qdw[a], acc);
  for (int d = lane; d < D_; d += 64) acc = fmaf(bq[d], bk[d], acc);
#pragma unroll
  for (int off = 1; off < 64; off <<= 1) acc += __shfl_xor(acc, off);
  if (lane == 0) out[m] = acc;
}

// ---------------------------------------------------------------------------
// Big bt-GEMM: C(bf16, MxN) = A(bf16 MxKd) @ Bw(bf16 NxKd)^T [+ bias].
// 128x128 tile, 4 waves, global_load_lds staging, both-sides XOR swizzle,
// XCD-chunked 1D grid (nwg % 8 == 0). Prologue-only (P^T, Wihv).
// ---------------------------------------------------------------------------
__global__ __launch_bounds__(256) void gemm128_bb(
    const u16* __restrict__ A, const u16* __restrict__ Bw,
    const float* __restrict__ bias, u16* __restrict__ C, int N, int Kd,
    int mtiles) {
  __shared__ __align__(16) u16 At[128 * 64];
  __shared__ __align__(16) u16 Bt[128 * 64];
  const int tid = threadIdx.x;
  const int ntiles = N >> 7;
  const int nwg = mtiles * ntiles;
  const int cpx = nwg >> 3;  // blocks per XCD (nwg % 8 == 0)
  const int lin = blockIdx.x;
  const int wg = (lin & 7) * cpx + (lin >> 3);
  const int m0 = (wg / ntiles) * 128;
  const int n0 = (wg % ntiles) * 128;
  const int wave = tid >> 6, lane = tid & 63;
  const int q4 = lane >> 4, l16 = lane & 15;
  const int wm = (wave & 1) * 64, wn = (wave >> 1) * 64;

  f32x4 acc[4][4];
#pragma unroll
  for (int i = 0; i < 4; ++i)
#pragma unroll
    for (int j = 0; j < 4; ++j) acc[i][j] = 0.f;

  const int trow = tid >> 3;                             // 0..31
  const int tcol = ((tid & 7) * 8) ^ ((trow & 7) << 3);  // pre-swizzled col
  const u16* ga = A + (size_t)(m0 + trow) * Kd + tcol;
  const u16* gb = Bw + (size_t)(n0 + trow) * Kd + tcol;
  u16* la = At + tid * 8;
  u16* lb = Bt + tid * 8;

  for (int k0 = 0; k0 < Kd; k0 += 64) {
    __syncthreads();
#pragma unroll
    for (int c = 0; c < 4; ++c)
      gload_lds16(ga + (size_t)c * 32 * Kd + k0, la + c * 2048);
#pragma unroll
    for (int c = 0; c < 4; ++c)
      gload_lds16(gb + (size_t)c * 32 * Kd + k0, lb + c * 2048);
    __syncthreads();
#pragma unroll
    for (int kk = 0; kk < 64; kk += 32) {
      bf16x8 af[4], bfr[4];
#pragma unroll
      for (int i = 0; i < 4; ++i) {
        const int row = wm + i * 16 + l16;
        const int byo = row * 128 + ((kk * 2 + q4 * 16) ^ ((row & 7) << 4));
        af[i] = *(const bf16x8*)((const char*)At + byo);
      }
#pragma unroll
      for (int j = 0; j < 4; ++j) {
        const int row = wn + j * 16 + l16;
        const int byo = row * 128 + ((kk * 2 + q4 * 16) ^ ((row & 7) << 4));
        bfr[j] = *(const bf16x8*)((const char*)Bt + byo);
      }
#pragma unroll
      for (int i = 0; i < 4; ++i)
#pragma unroll
        for (int j = 0; j < 4; ++j)
          acc[i][j] = __builtin_amdgcn_mfma_f32_16x16x32_bf16(af[i], bfr[j],
                                                              acc[i][j], 0, 0, 0);
    }
  }
#pragma unroll
  for (int j = 0; j < 4; ++j) {
    const int col = n0 + wn + j * 16 + l16;
    const float bv = bias ? bias[col] : 0.f;
#pragma unroll
    for (int i = 0; i < 4; ++i) {
      const int rowb = m0 + wm + i * 16 + q4 * 4;
#pragma unroll
      for (int r = 0; r < 4; ++r)
        C[(size_t)(rowb + r) * N + col] = f2b(acc[i][j][r] + bv);
    }
  }
}

// ---------------------------------------------------------------------------
// Small bt-GEMM (M=256): 64x64 tile, 4 waves of 32x32. A,Bw bf16, bias fp32.
// Reg-staged; both-sides XOR swizzle on LDS (write col ^ (row&7)<<3, read
// same) -> conflict-free ds_read_b128.
// MODE 0: bf16 out | 1: f32 out | 2: gelu->bf16 | 3: +resid -> f32
// ---------------------------------------------------------------------------
template <int MODE>
__global__ __launch_bounds__(256) void gemm64_bt(
    const u16* __restrict__ A, const u16* __restrict__ Bw,
    const float* __restrict__ bias, float* Cf, u16* Cb, const float* resid,
    int N, int Kd) {
  __shared__ __align__(16) u16 At[64 * 64];
  __shared__ __align__(16) u16 Bt[64 * 64];
  const int tid = threadIdx.x;
  const int m0 = blockIdx.x * 64;
  const int n0 = blockIdx.y * 64;
  const int wave = tid >> 6, lane = tid & 63;
  const int q4 = lane >> 4, l16 = lane & 15;
  const int wm = (wave & 1) * 32, wn = (wave >> 1) * 32;

  f32x4 acc[2][2];
#pragma unroll
  for (int i = 0; i < 2; ++i)
#pragma unroll
    for (int j = 0; j < 2; ++j) acc[i][j] = 0.f;

  const int r_ = tid >> 3;
  const int c8 = (tid & 7) * 8;
  const int c8s = c8 ^ ((r_ & 7) << 3);  // swizzled store col (row%8 == r_%8)

  for (int k0 = 0; k0 < Kd; k0 += 64) {
    u32x4 ta[2], tb[2];
#pragma unroll
    for (int i = 0; i < 2; ++i) {
      ta[i] = *(const u32x4*)(A + (size_t)(m0 + r_ + i * 32) * Kd + k0 + c8);
      tb[i] = *(const u32x4*)(Bw + (size_t)(n0 + r_ + i * 32) * Kd + k0 + c8);
    }
    __syncthreads();
#pragma unroll
    for (int i = 0; i < 2; ++i) {
      *(u32x4*)&At[(r_ + i * 32) * 64 + c8s] = ta[i];
      *(u32x4*)&Bt[(r_ + i * 32) * 64 + c8s] = tb[i];
    }
    __syncthreads();
#pragma unroll
    for (int kk = 0; kk < 64; kk += 32) {
      bf16x8 af[2], bfr[2];
#pragma unroll
      for (int i = 0; i < 2; ++i) {
        const int row = wm + i * 16 + l16;
        const int byo = row * 128 + ((kk * 2 + q4 * 16) ^ ((row & 7) << 4));
        af[i] = *(const bf16x8*)((const char*)At + byo);
      }
#pragma unroll
      for (int j = 0; j < 2; ++j) {
        const int row = wn + j * 16 + l16;
        const int byo = row * 128 + ((kk * 2 + q4 * 16) ^ ((row & 7) << 4));
        bfr[j] = *(const bf16x8*)((const char*)Bt + byo);
      }
#pragma unroll
      for (int i = 0; i < 2; ++i)
#pragma unroll
        for (int j = 0; j < 2; ++j)
          acc[i][j] = __builtin_amdgcn_mfma_f32_16x16x32_bf16(af[i], bfr[j],
                                                              acc[i][j], 0, 0, 0);
    }
  }
#pragma unroll
  for (int j = 0; j < 2; ++j) {
    const int col = n0 + wn + j * 16 + l16;
    const float bv = bias[col];
#pragma unroll
    for (int i = 0; i < 2; ++i) {
      const int rowb = m0 + wm + i * 16 + q4 * 4;
#pragma unroll
      for (int r = 0; r < 4; ++r) {
        const int row = rowb + r;
        float val = acc[i][j][r] + bv;
        if constexpr (MODE == 0) {
          Cb[(size_t)row * N + col] = f2b(val);
        } else if constexpr (MODE == 1) {
          Cf[(size_t)row * N + col] = val;
        } else if constexpr (MODE == 2) {
          val = 0.5f * val * (1.f + erff(val * 0.70710678118654752f));
          Cb[(size_t)row * N + col] = f2b(val);
        } else {
          const float rv = resid[(size_t)row * N + col];
          Cf[(size_t)row * N + col] = val + rv;
        }
      }
    }
  }
}

// ---------------------------------------------------------------------------
// attn pass 1: logits = qk@tok^T * SCALE + qdot, softmax over K (slots)
// -> attn_t (B,S,16) f32 + rowsum atomics; optional f32 attn (B,K,S) out.
// ---------------------------------------------------------------------------
__global__ __launch_bounds__(256) void attn_pass1(
    const u16* __restrict__ qb, const u16* __restrict__ tok,
    const float* __restrict__ qdot, float* __restrict__ attn_t,
    float* __restrict__ rowsum, float* __restrict__ attn_out) {
  const int b = blockIdx.y;
  const int wave = threadIdx.x >> 6, lane = threadIdx.x & 63;
  const int q4 = lane >> 4, l16 = lane & 15;
  const int tok0 = blockIdx.x * 256 + wave * 64;
  const u16* ap = qb + (size_t)(b * 16 + l16) * D_ + q4 * 8;
  const u16* bp = tok + ((size_t)b * S_ + tok0 + l16) * D_ + q4 * 8;
  const f32x4 qd = *(const f32x4*)&qdot[b * 16 + q4 * 4];
  f32x4 acc[4];
#pragma unroll
  for (int j = 0; j < 4; ++j) acc[j] = 0.f;
  for (int k0 = 0; k0 < D_; k0 += 32) {
    bf16x8 a = ld16g(ap + k0);
#pragma unroll
    for (int j = 0; j < 4; ++j) {
      bf16x8 bb = ld16g(bp + (size_t)j * 16 * D_ + k0);
      acc[j] = __builtin_amdgcn_mfma_f32_16x16x32_bf16(a, bb, acc[j], 0, 0, 0);
    }
  }
  float rs[4] = {0.f, 0.f, 0.f, 0.f};
#pragma unroll
  for (int j = 0; j < 4; ++j) {
    const int token = tok0 + j * 16 + l16;
    float l[4];
#pragma unroll
    for (int r = 0; r < 4; ++r) l[r] = acc[j][r] * SCALE_ + qd[r];
    float mx = fmaxf(fmaxf(l[0], l[1]), fmaxf(l[2], l[3]));
    mx = fmaxf(mx, __shfl_xor(mx, 16));
    mx = fmaxf(mx, __shfl_xor(mx, 32));
    float e[4], ssum = 0.f;
#pragma unroll
    for (int r = 0; r < 4; ++r) { e[r] = __expf(l[r] - mx); ssum += e[r]; }
    ssum += __shfl_xor(ssum, 16);
    ssum += __shfl_xor(ssum, 32);
    const float inv = 1.f / ssum;
    f32x4 p;
#pragma unroll
    for (int r = 0; r < 4; ++r) { p[r] = e[r] * inv; rs[r] += p[r]; }
    *(f32x4*)(attn_t + ((size_t)b * S_ + token) * 16 + q4 * 4) = p;
    if (attn_out) {
#pragma unroll
      for (int r = 0; r < 4; ++r)
        attn_out[(size_t)(b * 16 + q4 * 4 + r) * S_ + token] = p[r];
    }
  }
#pragma unroll
  for (int r = 0; r < 4; ++r) {
    float v = rs[r];
    v += __shfl_xor(v, 1);
    v += __shfl_xor(v, 2);
    v += __shfl_xor(v, 4);
    v += __shfl_xor(v, 8);
    if (l16 == 0) atomicAdd(&rowsum[b * 16 + q4 * 4 + r], v);
  }
}

// ---------------------------------------------------------------------------
// attn pass 2: uprime[b,k,e] += sum_s attn_t[b,s,k] * tok[b,s,e].
// ---------------------------------------------------------------------------
__global__ __launch_bounds__(256) void attn_pass2(
    const float* __restrict__ attn_t, const u16* __restrict__ tok,
    float* __restrict__ uprime) {
  const int b = blockIdx.y;
  const int dchunk = blockIdx.x & 1;
  const int ssplit = blockIdx.x >> 1;
  const int d = dchunk * 512 + threadIdx.x * 2;
  const int s0 = ssplit * 512;
  const u16* vp = tok + ((size_t)b * S_ + s0) * D_ + d;
  const float* ap = attn_t + ((size_t)b * S_ + s0) * 16;
  float acc0[16], acc1[16];
#pragma unroll
  for (int k = 0; k < 16; ++k) { acc0[k] = 0.f; acc1[k] = 0.f; }
#pragma unroll 4
  for (int s = 0; s < 512; ++s) {
    const u32 vv2 = *(const u32*)(vp + (size_t)s * D_);
    const float v0 = b2f((u16)(vv2 & 0xffffu));
    const float v1 = b2f((u16)(vv2 >> 16));
    const float* ar = ap + s * 16;
#pragma unroll
    for (int k = 0; k < 16; ++k) {
      const float a = ar[k];
      acc0[k] = fmaf(a, v0, acc0[k]);
      acc1[k] = fmaf(a, v1, acc1[k]);
    }
  }
#pragma unroll
  for (int k = 0; k < 16; ++k) {
    atomicAdd(&uprime[(size_t)(b * 16 + k) * D_ + d], acc0[k]);
    atomicAdd(&uprime[(size_t)(b * 16 + k) * D_ + d + 1], acc1[k]);
  }
}

__global__ void normcvt_kernel(const float* __restrict__ updates,
                               const float* __restrict__ rowsum,
                               u16* __restrict__ out) {
  const int idx = blockIdx.x * 256 + threadIdx.x;
  const int m = idx >> 10;
  const float inv = 1.f / (rowsum[m] + 1e-8f);
  out[idx] = f2b(updates[idx] * inv);
}

// LayerNorm (256,1024) f32 -> bf16 (+ optional raw bf16 copy). g,b fp32.
__global__ __launch_bounds__(256) void ln_kernel(
    const float* __restrict__ x, const float* __restrict__ g,
    const float* __restrict__ bb, u16* __restrict__ out_ln,
    u16* __restrict__ out_raw) {
  const int row = blockIdx.x, tid = threadIdx.x;
  const float* xr = x + (size_t)row * D_;
  float v[4], s = 0.f, ss = 0.f;
#pragma unroll
  for (int i = 0; i < 4; ++i) {
    v[i] = xr[tid + i * 256];
    s += v[i];
    ss += v[i] * v[i];
  }
#pragma unroll
  for (int off = 1; off < 64; off <<= 1) {
    s += __shfl_xor(s, off);
    ss += __shfl_xor(ss, off);
  }
  __shared__ float sh[8];
  if ((tid & 63) == 0) { sh[tid >> 6] = s; sh[4 + (tid >> 6)] = ss; }
  __syncthreads();
  s = sh[0] + sh[1] + sh[2] + sh[3];
  ss = sh[4] + sh[5] + sh[6] + sh[7];
  const float mu = s * (1.f / 1024.f);
  float var = ss * (1.f / 1024.f) - mu * mu;
  var = fmaxf(var, 0.f);
  const float rstd = rsqrtf(var + 1e-5f);
#pragma unroll
  for (int i = 0; i < 4; ++i) {
    const int dd = tid + i * 256;
    out_ln[(size_t)row * D_ + dd] =
        f2b((v[i] - mu) * rstd * g[dd] + bb[dd]);
    if (out_raw) out_raw[(size_t)row * D_ + dd] = f2b(v[i]);
  }
}

__global__ void gru_kernel(const float* __restrict__ gi,
                           const float* __restrict__ gh,
                           float* __restrict__ slots) {
  const int idx = blockIdx.x * 256 + threadIdx.x;
  const int m = idx >> 10, dd = idx & 1023;
  const size_t base = (size_t)m * 3072 + dd;
  const float ir = gi[base], iz = gi[base + 1024], in_ = gi[base + 2048];
  const float hr = gh[base], hz = gh[base + 1024], hn = gh[base + 2048];
  const float r = 1.f / (1.f + __expf(-(ir + hr)));
  const float z = 1.f / (1.f + __expf(-(iz + hz)));
  const float n = tanhf(in_ + r * hn);
  slots[idx] = (1.f - z) * n + z * slots[idx];
}

__global__ void init_slots_kernel(const float* __restrict__ mu,
                                  float* __restrict__ slots) {
  const int idx = blockIdx.x * 256 + threadIdx.x;
  slots[idx] = mu[idx & (K_ * D_ - 1)];
}

__global__ void store_slots_kernel(const float* __restrict__ slots,
                                   float* __restrict__ out) {
  const int idx = blockIdx.x * 256 + threadIdx.x;
  out[idx] = slots[idx];
}

// ---------------------------------------------------------------------------
extern "C" void kernel_launch(void* const* d_in, const int* in_sizes, int n_in,
                              void* d_out, int out_size, void* d_ws,
                              size_t ws_size, hipStream_t stream) {
  const float* tokens = (const float*)d_in[0];
  const float* slot_mu = (const float*)d_in[1];
  const float* Wq = (const float*)d_in[2];
  const float* bq = (const float*)d_in[3];
  const float* Wk = (const float*)d_in[4];
  const float* bk = (const float*)d_in[5];
  const float* Wv = (const float*)d_in[6];
  const float* bv = (const float*)d_in[7];
  const float* W_ih = (const float*)d_in[8];
  const float* b_ih = (const float*)d_in[9];
  const float* W_hh = (const float*)d_in[10];
  const float* b_hh = (const float*)d_in[11];
  const float* W1 = (const float*)d_in[12];
  const float* b1 = (const float*)d_in[13];
  const float* W2 = (const float*)d_in[14];
  const float* b2 = (const float*)d_in[15];
  const float* g_slots = (const float*)d_in[16];
  const float* b_slots = (const float*)d_in[17];
  const float* g_mlp = (const float*)d_in[18];
  const float* b_mlp = (const float*)d_in[19];

  char* p = (char*)d_ws;
  auto alloc = [&](size_t bytes) {
    char* r = p;
    p += (bytes + 255) & ~(size_t)255;
    return r;
  };
  u16* tokb = (u16*)alloc((size_t)B_ * S_ * D_ * 2);          // 134 MB bf16 tokens
  float* attn_t = (float*)alloc((size_t)B_ * S_ * K_ * 4);    // 4 MB
  float* slots = (float*)alloc((size_t)B_ * K_ * D_ * 4);     // 1 MB
  float* updates = (float*)alloc((size_t)B_ * K_ * D_ * 4);   // 1 MB (u')
  float* rowsum = (float*)alloc(1024);                        // adjacent to updates
  float* gi = (float*)alloc((size_t)B_ * K_ * 3 * D_ * 4);    // 3 MB
  float* gh = (float*)alloc((size_t)B_ * K_ * 3 * D_ * 4);    // 3 MB
  u16* slots_bf16 = (u16*)alloc((size_t)B_ * K_ * D_ * 2);
  u16* slots_ln_bf16 = (u16*)alloc((size_t)B_ * K_ * D_ * 2);
  u16* qkbuf = (u16*)alloc((size_t)B_ * K_ * D_ * 2);
  u16* updates_bf16 = (u16*)alloc((size_t)B_ * K_ * D_ * 2);
  u16* h_bf16 = (u16*)alloc((size_t)B_ * K_ * D_ * 2);
  u16* act_bf16 = (u16*)alloc((size_t)B_ * K_ * 4 * D_ * 2);  // 2 MB
  float* qdotbuf = (float*)alloc(256 * 4);
  float* qd_w = (float*)alloc(D_ * 4);
  float* qkbias = (float*)alloc(D_ * 4);
  float* bihv = (float*)alloc(3 * D_ * 4);
  // bf16 weight copies / fused products
  u16* cWih = (u16*)alloc((size_t)3 * D_ * D_ * 2);   // W_ih (for Wihv GEMM)
  u16* cWhh = (u16*)alloc((size_t)3 * D_ * D_ * 2);
  u16* cW1 = (u16*)alloc((size_t)4 * D_ * D_ * 2);
  u16* cW2 = (u16*)alloc((size_t)4 * D_ * D_ * 2);
  u16* cWqT = (u16*)alloc((size_t)D_ * D_ * 2);       // Wq^T
  u16* cWkT = (u16*)alloc((size_t)D_ * D_ * 2);       // Wk^T
  u16* cWvT = (u16*)alloc((size_t)D_ * D_ * 2);       // Wv^T
  u16* cPT = (u16*)alloc((size_t)D_ * D_ * 2);        // (Wq^T Wk)^T = Wk^T Wq
  u16* cWihv = (u16*)alloc((size_t)3 * D_ * D_ * 2);  // W_ih @ Wv
  if ((size_t)(p - (char*)d_ws) > ws_size) return;  // ws too small: bail

  float* out_slots = (float*)d_out;                        // (B,K,D) f32
  float* out_attn = (float*)d_out + (size_t)B_ * K_ * D_;  // (B,K,S) f32

  // ---- prologue: converts / transposes -----------------------------------
  convert8_kernel<<<(3 * D_ * D_ / 8 + 255) / 256, 256, 0, stream>>>(W_ih, cWih, 3 * D_ * D_ / 8);
  convert8_kernel<<<(3 * D_ * D_ / 8 + 255) / 256, 256, 0, stream>>>(W_hh, cWhh, 3 * D_ * D_ / 8);
  convert8_kernel<<<(4 * D_ * D_ / 8 + 255) / 256, 256, 0, stream>>>(W1, cW1, 4 * D_ * D_ / 8);
  convert8_kernel<<<(4 * D_ * D_ / 8 + 255) / 256, 256, 0, stream>>>(W2, cW2, 4 * D_ * D_ / 8);
  convert8_kernel<<<(B_ * S_ * D_ / 8 + 255) / 256, 256, 0, stream>>>(
      tokens, tokb, B_ * S_ * D_ / 8);
  transcvt_kernel<<<dim3(16, 16), 256, 0, stream>>>(Wq, cWqT, D_, D_);
  transcvt_kernel<<<dim3(16, 16), 256, 0, stream>>>(Wk, cWkT, D_, D_);
  transcvt_kernel<<<dim3(16, 16), 256, 0, stream>>>(Wv, cWvT, D_, D_);

  // fused weight products:
  // cPT[e,a] = sum_d Wk[d,e] Wq[d,a]  (so per-iter qk = lnS @ cPT^T)
  gemm128_bb<<<64, 256, 0, stream>>>(cWkT, cWqT, nullptr, cPT, D_, D_, 8);
  // cWihv[j,e] = sum_d W_ih[j,d] Wv[d,e]
  gemm128_bb<<<192, 256, 0, stream>>>(cWih, cWvT, nullptr, cWihv, D_, D_, 24);

  // bias folds (exact): qkbias[e] = bq.Wk[:,e]; qd_w[a] = Wq[:,a].bk;
  // bihv[j] = b_ih[j] + W_ih[j,:].bv   (split-R colvec: zero outputs first)
  hipMemsetAsync(qkbias, 0, D_ * 4, stream);
  hipMemsetAsync(qd_w, 0, D_ * 4, stream);
  colvec_kernel<<<dim3(4, 16), 256, 0, stream>>>(Wk, bq, qkbias, D_, D_);
  colvec_kernel<<<dim3(4, 16), 256, 0, stream>>>(Wq, bk, qd_w, D_, D_);
  rowvec_kernel<<<768, 256, 0, stream>>>(W_ih, bv, b_ih, bihv, 3 * D_, D_);

  init_slots_kernel<<<1024, 256, 0, stream>>>(slot_mu, slots);

  for (int it = 0; it < 3; ++it) {
    ln_kernel<<<256, 256, 0, stream>>>(slots, g_slots, b_slots, slots_ln_bf16,
                                       slots_bf16);
    // qk = lnS @ P + qkbias  (replaces q and k projections)
    gemm64_bt<0><<<dim3(4, 16), 256, 0, stream>>>(slots_ln_bf16, cPT, qkbias,
                                                  nullptr, qkbuf, nullptr, D_, D_);
    qdot_kernel<<<64, 256, 0, stream>>>(slots_ln_bf16, qd_w, bq, bk, qdotbuf);
    hipMemsetAsync(updates, 0, (size_t)B_ * K_ * D_ * 4 + 1024, stream);
    attn_pass1<<<dim3(16, 16), 256, 0, stream>>>(
        qkbuf, tokb, qdotbuf, attn_t, rowsum, (it == 2) ? out_attn : nullptr);
    attn_pass2<<<dim3(16, 16), 256, 0, stream>>>(attn_t, tokb, updates);
    normcvt_kernel<<<1024, 256, 0, stream>>>(updates, rowsum, updates_bf16);
    // gi = u'n @ Wihv^T + (W_ih bv + b_ih)   (V projection folded in)
    gemm64_bt<1><<<dim3(4, 48), 256, 0, stream>>>(updates_bf16, cWihv, bihv, gi,
                                                  nullptr, nullptr, 3 * D_, D_);
    gemm64_bt<1><<<dim3(4, 48), 256, 0, stream>>>(slots_bf16, cWhh, b_hh, gh,
                                                  nullptr, nullptr, 3 * D_, D_);
    gru_kernel<<<1024, 256, 0, stream>>>(gi, gh, slots);
    ln_kernel<<<256, 256, 0, stream>>>(slots, g_mlp, b_mlp, h_bf16, nullptr);
    gemm64_bt<2><<<dim3(4, 64), 256, 0, stream>>>(h_bf16, cW1, b1, nullptr,
                                                  act_bf16, nullptr, 4 * D_, D_);
    gemm64_bt<3><<<dim3(4, 16), 256, 0, stream>>>(act_bf16, cW2, b2, slots,
                                                  nullptr, slots, D_, 4 * D_);
  }
  store_slots_kernel<<<1024, 256, 0, stream>>>(slots, out_slots);
}